// Round 2
// baseline (817.715 us; speedup 1.0000x reference)
//
#include <hip/hip_runtime.h>

typedef float v4f __attribute__((ext_vector_type(4)));

namespace {
constexpr int B_     = 8;
constexpr int NT_    = 256;
constexpr int NX_    = 256;
constexpr int NREC_  = 64;
constexpr int PIECES = 32;             // vertical strips per batch (R9: was 8)
constexpr int IROWS  = 8;              // interior rows per strip
constexpr int G      = 8;              // ghost width = steps per round
constexpr int ROUNDS = NT_ / G;        // 32
constexpr int NB     = (IROWS + 2 * G) / 4;  // bands per block = 6
constexpr int NTHR   = NB * 64;        // 384 threads
constexpr int NBLK   = B_ * PIECES;    // 256 blocks = 1 per CU
constexpr float DT2  = 1e-6f;          // DT*DT
constexpr float KLAP = 1e-8f;          // DT*DT/(DH*DH)
constexpr size_t FLAGS_BYTES = 4096;
constexpr int RCAP = 6;
} // namespace

// lane i <- lane i-1 (shfl_up 1). Lane 0 gets 0.0f (bound_ctrl) -- masked by cf=0.
__device__ __forceinline__ float dpp_shr1(float v) {
    return __int_as_float(__builtin_amdgcn_update_dpp(
        0, __float_as_int(v), 0x138 /*WAVE_SHR1*/, 0xF, 0xF, true));
}
// lane i <- lane i+1 (shfl_down 1). Lane 63 gets 0.0f -- masked by cf=0.
__device__ __forceinline__ float dpp_shl1(float v) {
    return __int_as_float(__builtin_amdgcn_update_dpp(
        0, __float_as_int(v), 0x130 /*WAVE_SHL1*/, 0xF, 0xF, true));
}

// R9: 256 blocks (piece p of batch b, blockIdx = p*8 + b) -> one block per CU.
// Each block evolves 24 ext rows (8 interior + 8 ghost each side) in REGISTERS
// (4x4 tile per thread, both levels); LDS holds only band-boundary halo rows.
// Cross-block exchange every G=8 steps: interior (= exactly G rows) published
// once to gbuf, read by BOTH neighbors; agent-scope flag handshake (R6-proven).
// Neighbors are +-8 in blockIdx -> same XCD under round-robin -> L2-local.
extern "C" __global__
__attribute__((amdgpu_flat_work_group_size(NTHR, NTHR), amdgpu_waves_per_eu(4, 4)))
void wave_reg_kernel(const float* __restrict__ x,
                     const float* __restrict__ vp,
                     const int* __restrict__ src_loc,
                     const int* __restrict__ rec_loc,
                     float* __restrict__ out,
                     int* __restrict__ flags,   // [256] monotone round counters
                     float* __restrict__ gbuf)  // [par2][256][lvl2][8][256]
{
    __shared__ float pub[2][2][NB][256];   // 24 KB: [par][top/bot row][band][col]
    __shared__ float wav[NT_];             // 1 KB wavelet
    __shared__ float recbuf[G][NREC_];     // 2 KB receiver staging (per round)
    __shared__ unsigned char recown[NREC_];// per-rec ownership of this block

    const int bid  = blockIdx.x;
    const int b    = bid & 7;
    const int p    = bid >> 3;
    const int blk  = b * PIECES + p;
    const int tid  = threadIdx.x;
    const int band = tid >> 6;             // wave id 0..5 -> 4 ext rows
    const int lane = tid & 63;
    const int c0   = lane << 2;            // first owned col (0..252)
    const int grt  = p * IROWS - G + (band << 2);  // global row of owned row 0

    if (tid < NT_) wav[tid] = x[b * NT_ + tid];
    if (tid < NREC_) {
        int rz = rec_loc[(b * NREC_ + tid) * 2 + 0];
        recown[tid] = (rz >= p * IROWS && rz < p * IROWS + IROWS) ? 1 : 0;
    }

    // cf = vp^2*DT^2/DH^2, zeroed at Dirichlet boundary + out-of-domain rows
    v4f cf[4];
#pragma unroll
    for (int i = 0; i < 4; ++i) {
        int gr = grt + i;
        int crow = gr < 0 ? 0 : (gr > 255 ? 255 : gr);
        bool rowok = (gr >= 1) && (gr <= 254);
        v4f vv = *(const v4f*)&vp[crow * NX_ + c0];
        float cc[4];
#pragma unroll
        for (int k = 0; k < 4; ++k) {
            int col = c0 + k;
            float vk = (k == 0) ? vv.x : (k == 1) ? vv.y : (k == 2) ? vv.z : vv.w;
            cc[k] = (rowok && col >= 1 && col <= 254) ? vk * vk * KLAP : 0.f;
        }
        cf[i].x = cc[0]; cf[i].y = cc[1]; cf[i].z = cc[2]; cf[i].w = cc[3];
    }

    // source ownership (ghost rows included: ghost evolution must replay it)
    const int sz = src_loc[b * 2 + 0], sx = src_loc[b * 2 + 1];
    const int si = sz - grt;               // 0..3 if owned row
    const int sj = sx - c0;                // 0..3 if owned col
    const bool has_src = ((unsigned)si < 4u) && ((unsigned)sj < 4u);

    // receiver slots: interior owner only (unique writer). pk=(r<<4)|(i<<2)|j
    int rs[RCAP]; int rcnt = 0;
#pragma unroll 1
    for (int r = 0; r < NREC_; ++r) {
        int rz = rec_loc[(b * NREC_ + r) * 2 + 0];
        int rx = rec_loc[(b * NREC_ + r) * 2 + 1];
        int i = rz - grt, j = rx - c0;
        if (rz >= p * IROWS && rz < p * IROWS + IROWS &&
            (unsigned)i < 4u && (unsigned)j < 4u) {
            if (rcnt < RCAP) rs[rcnt] = (r << 4) | (i << 2) | j;
            ++rcnt;
        }
    }
    if (rcnt > RCAP) rcnt = RCAP;
    float* outb = out + (size_t)b * NT_ * NREC_;

    v4f A[4], Bv[4];
    {
        v4f z = {0.f, 0.f, 0.f, 0.f};
#pragma unroll
        for (int i = 0; i < 4; ++i) { A[i] = z; Bv[i] = z; }
    }

    // one step: P <- update(C, P); P becomes current. par = t&1.
    auto step = [&](v4f (&C)[4], v4f (&P)[4], int t, int par) {
        *(v4f*)&pub[par][0][band][c0] = C[0];   // my top row (south halo of band-1)
        *(v4f*)&pub[par][1][band][c0] = C[3];   // my bottom row (north halo of band+1)
        __syncthreads();
        v4f nn, ss;
        if (band > 0)      nn = *(const v4f*)&pub[par][1][band - 1][c0];
        else               { nn.x = 0.f; nn.y = 0.f; nn.z = 0.f; nn.w = 0.f; }
        if (band < NB - 1) ss = *(const v4f*)&pub[par][0][band + 1][c0];
        else               { ss.x = 0.f; ss.y = 0.f; ss.z = 0.f; ss.w = 0.f; }
        const float sv = DT2 * wav[t];
#pragma unroll
        for (int i = 0; i < 4; ++i) {
            v4f n = (i == 0) ? nn : C[i - 1];
            v4f s = (i == 3) ? ss : C[i + 1];
            float wv = dpp_shr1(C[i].w);   // col c0-1 (lane0 -> 0: cf=0 masks)
            float ev = dpp_shl1(C[i].x);   // col c0+4 (lane63 -> 0: cf=0 masks)
            v4f hn;
            { float sm = (n.x + s.x) + (wv     + C[i].y);
              hn.x = fmaf(cf[i].x, fmaf(-4.f, C[i].x, sm), fmaf(2.f, C[i].x, -P[i].x)); }
            { float sm = (n.y + s.y) + (C[i].x + C[i].z);
              hn.y = fmaf(cf[i].y, fmaf(-4.f, C[i].y, sm), fmaf(2.f, C[i].y, -P[i].y)); }
            { float sm = (n.z + s.z) + (C[i].y + C[i].w);
              hn.z = fmaf(cf[i].z, fmaf(-4.f, C[i].z, sm), fmaf(2.f, C[i].z, -P[i].z)); }
            { float sm = (n.w + s.w) + (C[i].z + ev);
              hn.w = fmaf(cf[i].w, fmaf(-4.f, C[i].w, sm), fmaf(2.f, C[i].w, -P[i].w)); }
            if (has_src && si == i) {
                if      (sj == 0) hn.x += sv;
                else if (sj == 1) hn.y += sv;
                else if (sj == 2) hn.z += sv;
                else              hn.w += sv;
            }
            P[i] = hn;
        }
        // receiver gather from the NEW level (registers) -> LDS staging only.
#pragma unroll
        for (int k = 0; k < RCAP; ++k) {
            if (rcnt > k) {
                int pk = rs[k];
                int i = (pk >> 2) & 3, j = pk & 3, r = pk >> 4;
                v4f t01 = (i & 1) ? P[1] : P[0];
                v4f t23 = (i & 1) ? P[3] : P[2];
                v4f rw  = (i & 2) ? t23 : t01;
                float c01 = (j & 1) ? rw.y : rw.x;
                float c23 = (j & 1) ? rw.w : rw.z;
                recbuf[t & (G - 1)][r] = (j & 2) ? c23 : c01;
            }
        }
        // no trailing barrier: next step uses pub[par^1] (parity double-buffer)
    };

    // ghost exchange after round e: A=cur(lvl0), B=prev(lvl1), regs <-> global.
    // Interior (8 rows) == exactly what BOTH neighbors need as ghost -> one slab.
    auto exchange = [&](int e) {
        auto gptr = [&](int bk, int lvl, int rr) -> float* {
            return gbuf + ((((size_t)(e & 1) * NBLK + bk) * 2 + lvl) * G + rr) * 256;
        };
        if (band == 2 || band == 3) {      // publish interior, both levels
            int rr0 = (band - 2) << 2;     // slab rows 0..3 / 4..7
#pragma unroll
            for (int i = 0; i < 4; ++i) {
                *(v4f*)&gptr(blk, 0, rr0 + i)[c0] = A[i];
                *(v4f*)&gptr(blk, 1, rr0 + i)[c0] = Bv[i];
            }
        }
        __syncthreads();                   // every wave's stores vmcnt-drained
        if (tid == 0) {
            __builtin_amdgcn_fence(__ATOMIC_RELEASE, "agent");
            __hip_atomic_store(&flags[blk], e + 1, __ATOMIC_RELEASE,
                               __HIP_MEMORY_SCOPE_AGENT);
            if (p > 0)
                while (__hip_atomic_load(&flags[blk - 1], __ATOMIC_ACQUIRE,
                                         __HIP_MEMORY_SCOPE_AGENT) < e + 1)
                    __builtin_amdgcn_s_sleep(8);
            __builtin_amdgcn_fence(__ATOMIC_ACQUIRE, "agent");
        }
        if (tid == 64 && p < PIECES - 1) { // second wave polls south in parallel
            while (__hip_atomic_load(&flags[blk + 1], __ATOMIC_ACQUIRE,
                                     __HIP_MEMORY_SCOPE_AGENT) < e + 1)
                __builtin_amdgcn_s_sleep(8);
            __builtin_amdgcn_fence(__ATOMIC_ACQUIRE, "agent");
        }
        __syncthreads();                   // all threads ordered after acquire
        if (band < 2 && p > 0) {           // top ghost <- north neighbor interior
            int rr0 = band << 2;           // ext rows 0..7 == blk-1 slab rows 0..7
#pragma unroll
            for (int i = 0; i < 4; ++i) {
                A[i]  = *(const v4f*)&gptr(blk - 1, 0, rr0 + i)[c0];
                Bv[i] = *(const v4f*)&gptr(blk - 1, 1, rr0 + i)[c0];
            }
        }
        if (band >= 4 && p < PIECES - 1) { // bottom ghost <- south neighbor
            int rr0 = (band - 4) << 2;     // ext rows 16..23 == blk+1 slab rows 0..7
#pragma unroll
            for (int i = 0; i < 4; ++i) {
                A[i]  = *(const v4f*)&gptr(blk + 1, 0, rr0 + i)[c0];
                Bv[i] = *(const v4f*)&gptr(blk + 1, 1, rr0 + i)[c0];
            }
        }
    };

    int t = 0;
#pragma unroll 1
    for (int e = 0; e < ROUNDS; ++e) {
#pragma unroll 1
        for (int s = 0; s < G; s += 2) {
            step(A, Bv, t, 0);      // t even: cur=A, par=0
            step(Bv, A, t + 1, 1);  // t odd:  cur=B, par=1
            t += 2;
        }
        // flush this round's receiver samples (G*NREC = 512 slots, 384 threads).
        __syncthreads();           // recbuf writes came from scattered owners
#pragma unroll 1
        for (int idx = tid; idx < G * NREC_; idx += NTHR) {
            int s = idx >> 6, r = idx & 63;
            if (recown[r]) outb[(e * G + s) * NREC_ + r] = recbuf[s][r];
        }
        // next recbuf writes are ordered behind exchange's two __syncthreads;
        // last round ends the kernel.
        if (e < ROUNDS - 1) exchange(e);
    }
}

extern "C" void kernel_launch(void* const* d_in, const int* in_sizes, int n_in,
                              void* d_out, int out_size, void* d_ws, size_t ws_size,
                              hipStream_t stream) {
    const float* x   = (const float*)d_in[0];
    const float* vp  = (const float*)d_in[1];
    const int*   src = (const int*)d_in[2];
    const int*   rec = (const int*)d_in[3];
    float*       o   = (float*)d_out;
    int*   flags = (int*)d_ws;
    float* gbuf  = (float*)((char*)d_ws + FLAGS_BYTES);
    (void)hipMemsetAsync(d_ws, 0, FLAGS_BYTES, stream);   // flags must start at 0
    hipLaunchKernelGGL(wave_reg_kernel, dim3(NBLK), dim3(NTHR), 0, stream,
                       x, vp, src, rec, o, flags, gbuf);
}

// Round 3
// 360.903 us; speedup vs baseline: 2.2657x; 2.2657x over previous
//
#include <hip/hip_runtime.h>

typedef float v4f __attribute__((ext_vector_type(4)));

namespace {
constexpr int B_     = 8;
constexpr int NT_    = 256;
constexpr int NX_    = 256;
constexpr int NREC_  = 64;
constexpr int PIECES = 8;              // vertical strips per batch (R8-proven)
constexpr int IROWS  = 32;             // interior rows per strip
constexpr int G      = 16;             // ghost width = steps per round
constexpr int ROUNDS = NT_ / G;        // 16
constexpr float DT2  = 1e-6f;          // DT*DT
constexpr float KLAP = 1e-8f;          // DT*DT/(DH*DH)
constexpr size_t FLAGS_BYTES = 4096;
constexpr int RCAP = 6;
} // namespace

// lane i <- lane i-1 (shfl_up 1). Lane 0 gets 0.0f (bound_ctrl) -- masked by cf=0.
__device__ __forceinline__ float dpp_shr1(float v) {
    return __int_as_float(__builtin_amdgcn_update_dpp(
        0, __float_as_int(v), 0x138 /*WAVE_SHR1*/, 0xF, 0xF, true));
}
// lane i <- lane i+1 (shfl_down 1). Lane 63 gets 0.0f -- masked by cf=0.
__device__ __forceinline__ float dpp_shl1(float v) {
    return __int_as_float(__builtin_amdgcn_update_dpp(
        0, __float_as_int(v), 0x130 /*WAVE_SHL1*/, 0xF, 0xF, true));
}

// R10: fence-free exchange. gbuf traffic goes through the MALL (L3) via
// sc0 sc1 (system-coherent) loads/stores that bypass the non-coherent per-XCD
// L2s entirely. No agent-scope release/acquire fences -> no buffer_wbl2 /
// buffer_inv storms (R9 post-mortem: those cost ~12-20us PER EXCHANGE, scaling
// with blocks-per-XCD). Ordering: __syncthreads drains vmcnt to the coherence
// point before the flag store; poll's data-dependent branch orders refills.
__device__ __forceinline__ void store_v4_sys(float* p, v4f v) {
    asm volatile("global_store_dwordx4 %0, %1, off sc0 sc1"
                 :: "v"(p), "v"(v) : "memory");
}
__device__ __forceinline__ v4f load_v4_sys(const float* p) {
    v4f r;
    asm volatile("global_load_dwordx4 %0, %1, off sc0 sc1"
                 : "=v"(r) : "v"(p) : "memory");
    return r;
}

extern "C" __global__
__attribute__((amdgpu_flat_work_group_size(1024, 1024), amdgpu_waves_per_eu(4, 4)))
void wave_reg_kernel(const float* __restrict__ x,
                     const float* __restrict__ vp,
                     const int* __restrict__ src_loc,
                     const int* __restrict__ rec_loc,
                     float* __restrict__ out,
                     int* __restrict__ flags,   // [64] monotone round counters
                     float* __restrict__ gbuf)  // [par2][64][side2][lvl2][16][256]
{
    __shared__ float pub[2][2][16][256];   // 64 KB: [par][top/bot row][band][col]
    __shared__ float wav[NT_];             // 1 KB wavelet
    __shared__ float recbuf[G][NREC_];     // 4 KB receiver staging (per round)
    __shared__ unsigned char recown[NREC_];// per-rec ownership of this block

    const int bid  = blockIdx.x;
    const int b    = bid & 7;
    const int p    = bid >> 3;
    const int blk  = b * PIECES + p;
    const int tid  = threadIdx.x;
    const int band = tid >> 6;             // wave id 0..15 -> 4 ext rows
    const int lane = tid & 63;
    const int c0   = lane << 2;            // first owned col (0..252)
    const int grt  = p * IROWS - G + (band << 2);  // global row of owned row 0

    if (tid < NT_) wav[tid] = x[b * NT_ + tid];
    if (tid < NREC_) {
        int rz = rec_loc[(b * NREC_ + tid) * 2 + 0];
        recown[tid] = (rz >= p * IROWS && rz < p * IROWS + IROWS) ? 1 : 0;
    }

    // cf = vp^2*DT^2/DH^2, zeroed at Dirichlet boundary + out-of-domain rows
    v4f cf[4];
#pragma unroll
    for (int i = 0; i < 4; ++i) {
        int gr = grt + i;
        int crow = gr < 0 ? 0 : (gr > 255 ? 255 : gr);
        bool rowok = (gr >= 1) && (gr <= 254);
        v4f vv = *(const v4f*)&vp[crow * NX_ + c0];
        float cc[4];
#pragma unroll
        for (int k = 0; k < 4; ++k) {
            int col = c0 + k;
            float vk = (k == 0) ? vv.x : (k == 1) ? vv.y : (k == 2) ? vv.z : vv.w;
            cc[k] = (rowok && col >= 1 && col <= 254) ? vk * vk * KLAP : 0.f;
        }
        cf[i].x = cc[0]; cf[i].y = cc[1]; cf[i].z = cc[2]; cf[i].w = cc[3];
    }

    // source ownership (ghost rows included: ghost evolution must replay it)
    const int sz = src_loc[b * 2 + 0], sx = src_loc[b * 2 + 1];
    const int si = sz - grt;               // 0..3 if owned row
    const int sj = sx - c0;                // 0..3 if owned col
    const bool has_src = ((unsigned)si < 4u) && ((unsigned)sj < 4u);

    // receiver slots: interior owner only (unique writer). pk=(r<<4)|(i<<2)|j
    int rs[RCAP]; int rcnt = 0;
#pragma unroll 1
    for (int r = 0; r < NREC_; ++r) {
        int rz = rec_loc[(b * NREC_ + r) * 2 + 0];
        int rx = rec_loc[(b * NREC_ + r) * 2 + 1];
        int i = rz - grt, j = rx - c0;
        if (rz >= p * IROWS && rz < p * IROWS + IROWS &&
            (unsigned)i < 4u && (unsigned)j < 4u) {
            if (rcnt < RCAP) rs[rcnt] = (r << 4) | (i << 2) | j;
            ++rcnt;
        }
    }
    if (rcnt > RCAP) rcnt = RCAP;
    float* outb = out + (size_t)b * NT_ * NREC_;

    v4f A[4], Bv[4];
    {
        v4f z = {0.f, 0.f, 0.f, 0.f};
#pragma unroll
        for (int i = 0; i < 4; ++i) { A[i] = z; Bv[i] = z; }
    }

    // one step: P <- update(C, P); P becomes current. par = t&1.
    auto step = [&](v4f (&C)[4], v4f (&P)[4], int t, int par) {
        *(v4f*)&pub[par][0][band][c0] = C[0];   // my top row (south halo of band-1)
        *(v4f*)&pub[par][1][band][c0] = C[3];   // my bottom row (north halo of band+1)
        __syncthreads();
        v4f nn, ss;
        if (band > 0)  nn = *(const v4f*)&pub[par][1][band - 1][c0];
        else           { nn.x = 0.f; nn.y = 0.f; nn.z = 0.f; nn.w = 0.f; }
        if (band < 15) ss = *(const v4f*)&pub[par][0][band + 1][c0];
        else           { ss.x = 0.f; ss.y = 0.f; ss.z = 0.f; ss.w = 0.f; }
        const float sv = DT2 * wav[t];
#pragma unroll
        for (int i = 0; i < 4; ++i) {
            v4f n = (i == 0) ? nn : C[i - 1];
            v4f s = (i == 3) ? ss : C[i + 1];
            float wv = dpp_shr1(C[i].w);   // col c0-1 (lane0 -> 0: cf=0 masks)
            float ev = dpp_shl1(C[i].x);   // col c0+4 (lane63 -> 0: cf=0 masks)
            v4f hn;
            { float sm = (n.x + s.x) + (wv     + C[i].y);
              hn.x = fmaf(cf[i].x, fmaf(-4.f, C[i].x, sm), fmaf(2.f, C[i].x, -P[i].x)); }
            { float sm = (n.y + s.y) + (C[i].x + C[i].z);
              hn.y = fmaf(cf[i].y, fmaf(-4.f, C[i].y, sm), fmaf(2.f, C[i].y, -P[i].y)); }
            { float sm = (n.z + s.z) + (C[i].y + C[i].w);
              hn.z = fmaf(cf[i].z, fmaf(-4.f, C[i].z, sm), fmaf(2.f, C[i].z, -P[i].z)); }
            { float sm = (n.w + s.w) + (C[i].z + ev);
              hn.w = fmaf(cf[i].w, fmaf(-4.f, C[i].w, sm), fmaf(2.f, C[i].w, -P[i].w)); }
            if (has_src && si == i) {
                if      (sj == 0) hn.x += sv;
                else if (sj == 1) hn.y += sv;
                else if (sj == 2) hn.z += sv;
                else              hn.w += sv;
            }
            P[i] = hn;
        }
        // receiver gather from the NEW level (registers) -> LDS staging only.
#pragma unroll
        for (int k = 0; k < RCAP; ++k) {
            if (rcnt > k) {
                int pk = rs[k];
                int i = (pk >> 2) & 3, j = pk & 3, r = pk >> 4;
                v4f t01 = (i & 1) ? P[1] : P[0];
                v4f t23 = (i & 1) ? P[3] : P[2];
                v4f rw  = (i & 2) ? t23 : t01;
                float c01 = (j & 1) ? rw.y : rw.x;
                float c23 = (j & 1) ? rw.w : rw.z;
                recbuf[t & (G - 1)][r] = (j & 2) ? c23 : c01;
            }
        }
        // no trailing barrier: next step uses pub[par^1] (parity double-buffer)
    };

    // ghost exchange after round e: A=cur(lvl0), B=prev(lvl1), regs <-> L3.
    // All gbuf traffic is sc0 sc1 (bypasses L1+L2, lives in MALL) -> no cache
    // maintenance needed. Flags are RELAXED system-scope atomics (no fences).
    auto exchange = [&](int e) {
        auto gptr = [&](int bk, int side, int lvl, int rr) -> float* {
            return gbuf + (((((size_t)(e & 1) * 64 + bk) * 2 + side) * 2 + lvl)
                           * 16 + rr) * 256;
        };
        if (band >= 4 && band < 12) {      // publish interior halves, both levels
            int side = (band >= 8) ? 1 : 0;
            int rr0 = (band << 2) - (side ? 32 : 16);
#pragma unroll
            for (int i = 0; i < 4; ++i) {
                store_v4_sys(&gptr(blk, side, 0, rr0 + i)[c0], A[i]);
                store_v4_sys(&gptr(blk, side, 1, rr0 + i)[c0], Bv[i]);
            }
        }
        // __syncthreads semantics: every wave does s_waitcnt vmcnt(0) before
        // s_barrier -> all sc0 sc1 stores ack'd at the coherence point (MALL)
        // before any thread proceeds to the flag store.
        __syncthreads();
        if (tid == 0) {
            __hip_atomic_store(&flags[blk], e + 1, __ATOMIC_RELAXED,
                               __HIP_MEMORY_SCOPE_SYSTEM);
            if (p > 0)
                while (__hip_atomic_load(&flags[blk - 1], __ATOMIC_RELAXED,
                                         __HIP_MEMORY_SCOPE_SYSTEM) < e + 1)
                    __builtin_amdgcn_s_sleep(1);
        }
        if (tid == 64 && p < PIECES - 1) { // second wave polls south in parallel
            while (__hip_atomic_load(&flags[blk + 1], __ATOMIC_RELAXED,
                                     __HIP_MEMORY_SCOPE_SYSTEM) < e + 1)
                __builtin_amdgcn_s_sleep(1);
        }
        __syncthreads();                   // all threads ordered after the polls
        if (band < 4 && p > 0) {           // refill top ghost from north neighbor
            int rr0 = band << 2;
#pragma unroll
            for (int i = 0; i < 4; ++i) {
                A[i]  = load_v4_sys(&gptr(blk - 1, 1, 0, rr0 + i)[c0]);
                Bv[i] = load_v4_sys(&gptr(blk - 1, 1, 1, rr0 + i)[c0]);
            }
        }
        if (band >= 12 && p < PIECES - 1) {  // refill bottom ghost from south
            int rr0 = (band << 2) - 48;
#pragma unroll
            for (int i = 0; i < 4; ++i) {
                A[i]  = load_v4_sys(&gptr(blk + 1, 0, 0, rr0 + i)[c0]);
                Bv[i] = load_v4_sys(&gptr(blk + 1, 0, 1, rr0 + i)[c0]);
            }
        }
        // asm loads are opaque to the compiler's waitcnt insertion: drain vmcnt
        // before anything reads A/Bv, and pin the order (rule #18).
        asm volatile("s_waitcnt vmcnt(0)" ::: "memory");
        __builtin_amdgcn_sched_barrier(0);
    };

    int t = 0;
#pragma unroll 1
    for (int e = 0; e < ROUNDS; ++e) {
#pragma unroll 1
        for (int s = 0; s < G; s += 2) {
            step(A, Bv, t, 0);      // t even: cur=A, par=0
            step(Bv, A, t + 1, 1);  // t odd:  cur=B, par=1
            t += 2;
        }
        // flush this round's receiver samples: one coalesced masked store.
        __syncthreads();           // recbuf writes came from scattered owners
        {
            int s = tid >> 6;      // 0..15 = step within round
            int r = tid & 63;      // 0..63 = receiver
            if (recown[r]) outb[(e * G + s) * NREC_ + r] = recbuf[s][r];
        }
        // next recbuf writes are ordered behind exchange's two __syncthreads;
        // last round ends the kernel.
        if (e < ROUNDS - 1) exchange(e);
    }
}

extern "C" void kernel_launch(void* const* d_in, const int* in_sizes, int n_in,
                              void* d_out, int out_size, void* d_ws, size_t ws_size,
                              hipStream_t stream) {
    const float* x   = (const float*)d_in[0];
    const float* vp  = (const float*)d_in[1];
    const int*   src = (const int*)d_in[2];
    const int*   rec = (const int*)d_in[3];
    float*       o   = (float*)d_out;
    int*   flags = (int*)d_ws;
    float* gbuf  = (float*)((char*)d_ws + FLAGS_BYTES);
    (void)hipMemsetAsync(d_ws, 0, FLAGS_BYTES, stream);   // flags must start at 0
    hipLaunchKernelGGL(wave_reg_kernel, dim3(B_ * PIECES), dim3(1024), 0, stream,
                       x, vp, src, rec, o, flags, gbuf);
}

// Round 4
// 346.731 us; speedup vs baseline: 2.3584x; 1.0409x over previous
//
#include <hip/hip_runtime.h>

typedef float v4f __attribute__((ext_vector_type(4)));

namespace {
constexpr int B_     = 8;
constexpr int NT_    = 256;
constexpr int NX_    = 256;
constexpr int NREC_  = 64;
constexpr int PIECES = 8;              // vertical strips per batch (R8-proven)
constexpr int IROWS  = 32;             // interior rows per strip
constexpr int G      = 16;             // ghost width = steps per round
constexpr int ROUNDS = NT_ / G;        // 16
constexpr float DT2  = 1e-6f;          // DT*DT
constexpr float KLAP = 1e-8f;          // DT*DT/(DH*DH)
constexpr size_t FLAGS_BYTES = 4096;
constexpr int RCAP = 6;
} // namespace

// lane i <- lane i-1 (shfl_up 1). Lane 0 gets 0.0f (bound_ctrl) -- masked by cf=0.
__device__ __forceinline__ float dpp_shr1(float v) {
    return __int_as_float(__builtin_amdgcn_update_dpp(
        0, __float_as_int(v), 0x138 /*WAVE_SHR1*/, 0xF, 0xF, true));
}
// lane i <- lane i+1 (shfl_down 1). Lane 63 gets 0.0f -- masked by cf=0.
__device__ __forceinline__ float dpp_shl1(float v) {
    return __int_as_float(__builtin_amdgcn_update_dpp(
        0, __float_as_int(v), 0x130 /*WAVE_SHL1*/, 0xF, 0xF, true));
}

// R10: fence-free exchange via sc0 sc1 (system-coherent, bypasses the
// non-coherent per-XCD L2s). No buffer_wbl2/inv storms (R9 lesson: agent
// fences cost 12-20us PER EXCHANGE). R10 counters: steps are ~100%
// VALU-issue-bound (185us), exchanges ~8us each (120us total).
// R11: (1) cf2 algebra cuts stencil VALU 6->5 ops/col; (2) prev level (Bv)
// published EARLY (before the round's last step) so its store drain overlaps
// compute; (3) single-barrier wave-parallel handshake: ghost waves poll their
// own neighbor flag and refill immediately -- no serialized tid0/tid64 poll,
// one less block barrier per exchange.
__device__ __forceinline__ void store_v4_sys(float* p, v4f v) {
    asm volatile("global_store_dwordx4 %0, %1, off sc0 sc1"
                 :: "v"(p), "v"(v) : "memory");
}
__device__ __forceinline__ v4f load_v4_sys(const float* p) {
    v4f r;
    asm volatile("global_load_dwordx4 %0, %1, off sc0 sc1"
                 : "=v"(r) : "v"(p) : "memory");
    return r;
}

extern "C" __global__
__attribute__((amdgpu_flat_work_group_size(1024, 1024), amdgpu_waves_per_eu(4, 4)))
void wave_reg_kernel(const float* __restrict__ x,
                     const float* __restrict__ vp,
                     const int* __restrict__ src_loc,
                     const int* __restrict__ rec_loc,
                     float* __restrict__ out,
                     int* __restrict__ flags,   // [64] monotone round counters
                     float* __restrict__ gbuf)  // [par2][64][side2][lvl2][16][256]
{
    __shared__ float pub[2][2][16][256];   // 64 KB: [par][top/bot row][band][col]
    __shared__ float wav[NT_];             // 1 KB wavelet
    __shared__ float recbuf[G][NREC_];     // 4 KB receiver staging (per round)
    __shared__ unsigned char recown[NREC_];// per-rec ownership of this block

    const int bid  = blockIdx.x;
    const int b    = bid & 7;
    const int p    = bid >> 3;
    const int blk  = b * PIECES + p;
    const int tid  = threadIdx.x;
    const int band = tid >> 6;             // wave id 0..15 -> 4 ext rows
    const int lane = tid & 63;
    const int c0   = lane << 2;            // first owned col (0..252)
    const int grt  = p * IROWS - G + (band << 2);  // global row of owned row 0

    if (tid < NT_) wav[tid] = x[b * NT_ + tid];
    if (tid < NREC_) {
        int rz = rec_loc[(b * NREC_ + tid) * 2 + 0];
        recown[tid] = (rz >= p * IROWS && rz < p * IROWS + IROWS) ? 1 : 0;
    }

    // cf = vp^2*DT^2/DH^2, zeroed at Dirichlet boundary + out-of-domain rows.
    // cf2 = 2 - 4*cf: hn = cf*((N+S)+(E+W)) + (cf2*C - P)  [5 VALU/col vs 6]
    v4f cf[4], cf2[4];
#pragma unroll
    for (int i = 0; i < 4; ++i) {
        int gr = grt + i;
        int crow = gr < 0 ? 0 : (gr > 255 ? 255 : gr);
        bool rowok = (gr >= 1) && (gr <= 254);
        v4f vv = *(const v4f*)&vp[crow * NX_ + c0];
        float cc[4];
#pragma unroll
        for (int k = 0; k < 4; ++k) {
            int col = c0 + k;
            float vk = (k == 0) ? vv.x : (k == 1) ? vv.y : (k == 2) ? vv.z : vv.w;
            cc[k] = (rowok && col >= 1 && col <= 254) ? vk * vk * KLAP : 0.f;
        }
        cf[i].x = cc[0]; cf[i].y = cc[1]; cf[i].z = cc[2]; cf[i].w = cc[3];
        cf2[i].x = 2.f - 4.f * cc[0]; cf2[i].y = 2.f - 4.f * cc[1];
        cf2[i].z = 2.f - 4.f * cc[2]; cf2[i].w = 2.f - 4.f * cc[3];
    }

    // source ownership (ghost rows included: ghost evolution must replay it)
    const int sz = src_loc[b * 2 + 0], sx = src_loc[b * 2 + 1];
    const int si = sz - grt;               // 0..3 if owned row
    const int sj = sx - c0;                // 0..3 if owned col
    const bool has_src = ((unsigned)si < 4u) && ((unsigned)sj < 4u);

    // receiver slots: interior owner only (unique writer). pk=(r<<4)|(i<<2)|j
    int rs[RCAP]; int rcnt = 0;
#pragma unroll 1
    for (int r = 0; r < NREC_; ++r) {
        int rz = rec_loc[(b * NREC_ + r) * 2 + 0];
        int rx = rec_loc[(b * NREC_ + r) * 2 + 1];
        int i = rz - grt, j = rx - c0;
        if (rz >= p * IROWS && rz < p * IROWS + IROWS &&
            (unsigned)i < 4u && (unsigned)j < 4u) {
            if (rcnt < RCAP) rs[rcnt] = (r << 4) | (i << 2) | j;
            ++rcnt;
        }
    }
    if (rcnt > RCAP) rcnt = RCAP;
    float* outb = out + (size_t)b * NT_ * NREC_;

    v4f A[4], Bv[4];
    {
        v4f z = {0.f, 0.f, 0.f, 0.f};
#pragma unroll
        for (int i = 0; i < 4; ++i) { A[i] = z; Bv[i] = z; }
    }

    // gbuf slab pointer: [par][blk][side][lvl][row][col]
    auto gptr = [&](int e, int bk, int side, int lvl, int rr) -> float* {
        return gbuf + (((((size_t)(e & 1) * 64 + bk) * 2 + side) * 2 + lvl)
                       * 16 + rr) * 256;
    };

    // one step: P <- update(C, P); P becomes current. par = t&1.
    auto step = [&](v4f (&C)[4], v4f (&P)[4], int t, int par) {
        *(v4f*)&pub[par][0][band][c0] = C[0];   // my top row (south halo of band-1)
        *(v4f*)&pub[par][1][band][c0] = C[3];   // my bottom row (north halo of band+1)
        __syncthreads();
        v4f nn, ss;
        if (band > 0)  nn = *(const v4f*)&pub[par][1][band - 1][c0];
        else           { nn.x = 0.f; nn.y = 0.f; nn.z = 0.f; nn.w = 0.f; }
        if (band < 15) ss = *(const v4f*)&pub[par][0][band + 1][c0];
        else           { ss.x = 0.f; ss.y = 0.f; ss.z = 0.f; ss.w = 0.f; }
        const float sv = DT2 * wav[t];
#pragma unroll
        for (int i = 0; i < 4; ++i) {
            v4f n = (i == 0) ? nn : C[i - 1];
            v4f s = (i == 3) ? ss : C[i + 1];
            float wv = dpp_shr1(C[i].w);   // col c0-1 (lane0 -> 0: cf=0 masks)
            float ev = dpp_shl1(C[i].x);   // col c0+4 (lane63 -> 0: cf=0 masks)
            v4f hn;
            { float sm = (n.x + s.x) + (wv     + C[i].y);
              hn.x = fmaf(cf[i].x, sm, fmaf(cf2[i].x, C[i].x, -P[i].x)); }
            { float sm = (n.y + s.y) + (C[i].x + C[i].z);
              hn.y = fmaf(cf[i].y, sm, fmaf(cf2[i].y, C[i].y, -P[i].y)); }
            { float sm = (n.z + s.z) + (C[i].y + C[i].w);
              hn.z = fmaf(cf[i].z, sm, fmaf(cf2[i].z, C[i].z, -P[i].z)); }
            { float sm = (n.w + s.w) + (C[i].z + ev);
              hn.w = fmaf(cf[i].w, sm, fmaf(cf2[i].w, C[i].w, -P[i].w)); }
            if (has_src && si == i) {
                if      (sj == 0) hn.x += sv;
                else if (sj == 1) hn.y += sv;
                else if (sj == 2) hn.z += sv;
                else              hn.w += sv;
            }
            P[i] = hn;
        }
        // receiver gather from the NEW level (registers) -> LDS staging only.
#pragma unroll
        for (int k = 0; k < RCAP; ++k) {
            if (rcnt > k) {
                int pk = rs[k];
                int i = (pk >> 2) & 3, j = pk & 3, r = pk >> 4;
                v4f t01 = (i & 1) ? P[1] : P[0];
                v4f t23 = (i & 1) ? P[3] : P[2];
                v4f rw  = (i & 2) ? t23 : t01;
                float c01 = (j & 1) ? rw.y : rw.x;
                float c23 = (j & 1) ? rw.w : rw.z;
                recbuf[t & (G - 1)][r] = (j & 2) ? c23 : c01;
            }
        }
        // no trailing barrier: next step uses pub[par^1] (parity double-buffer)
    };

    // early publish of the prev level (Bv == lvl t_end-1, final after the first
    // step of the round's last pair). Store drain overlaps the last step.
    auto publish_prev = [&](int e) {
        if (band >= 4 && band < 12) {
            int side = (band >= 8) ? 1 : 0;
            int rr0 = (band << 2) - (side ? 32 : 16);
#pragma unroll
            for (int i = 0; i < 4; ++i)
                store_v4_sys(&gptr(e, blk, side, 1, rr0 + i)[c0], Bv[i]);
        }
    };

    // exchange after round e: publish cur (A), drain everything via the
    // barrier's vmcnt(0), flag (fire-and-forget), ghost waves poll + refill.
    auto exchange = [&](int e) {
        if (band >= 4 && band < 12) {      // publish interior halves, cur level
            int side = (band >= 8) ? 1 : 0;
            int rr0 = (band << 2) - (side ? 32 : 16);
#pragma unroll
            for (int i = 0; i < 4; ++i)
                store_v4_sys(&gptr(e, blk, side, 0, rr0 + i)[c0], A[i]);
        }
        // barrier semantics: each wave drains vmcnt(0) (all sc0 sc1 stores,
        // incl. the early Bv publish, ack'd at coherence point) before s_barrier.
        __syncthreads();
        if (tid == 0)                      // fire-and-forget; neighbors poll
            __hip_atomic_store(&flags[blk], e + 1, __ATOMIC_RELAXED,
                               __HIP_MEMORY_SCOPE_SYSTEM);
        if (band < 4 && p > 0) {           // top ghost <- north (blk-1)
            if (lane == 0)
                while (__hip_atomic_load(&flags[blk - 1], __ATOMIC_RELAXED,
                                         __HIP_MEMORY_SCOPE_SYSTEM) < e + 1)
                    __builtin_amdgcn_s_sleep(1);
            // wave reconverges here; refill loads are control-dependent on poll
            int rr0 = band << 2;
#pragma unroll
            for (int i = 0; i < 4; ++i) {
                A[i]  = load_v4_sys(&gptr(e, blk - 1, 1, 0, rr0 + i)[c0]);
                Bv[i] = load_v4_sys(&gptr(e, blk - 1, 1, 1, rr0 + i)[c0]);
            }
        }
        if (band >= 12 && p < PIECES - 1) {  // bottom ghost <- south (blk+1)
            if (lane == 0)
                while (__hip_atomic_load(&flags[blk + 1], __ATOMIC_RELAXED,
                                         __HIP_MEMORY_SCOPE_SYSTEM) < e + 1)
                    __builtin_amdgcn_s_sleep(1);
            int rr0 = (band << 2) - 48;
#pragma unroll
            for (int i = 0; i < 4; ++i) {
                A[i]  = load_v4_sys(&gptr(e, blk + 1, 0, 0, rr0 + i)[c0]);
                Bv[i] = load_v4_sys(&gptr(e, blk + 1, 0, 1, rr0 + i)[c0]);
            }
        }
        // asm loads are opaque to the compiler's waitcnt logic: drain before
        // any use of A/Bv and pin the order (rule #18).
        asm volatile("s_waitcnt vmcnt(0)" ::: "memory");
        __builtin_amdgcn_sched_barrier(0);
        __syncthreads();                   // all waves aligned for next round
    };

    int t = 0;
#pragma unroll 1
    for (int e = 0; e < ROUNDS; ++e) {
#pragma unroll 1
        for (int s = 0; s < G; s += 2) {
            step(A, Bv, t, 0);      // t even: cur=A, par=0
            if (s == G - 2 && e < ROUNDS - 1)
                publish_prev(e);    // Bv = lvl t_end-1 is final; overlap drain
            step(Bv, A, t + 1, 1);  // t odd:  cur=B, par=1
            t += 2;
        }
        // flush this round's receiver samples: one coalesced masked store.
        __syncthreads();           // recbuf writes came from scattered owners
        {
            int s = tid >> 6;      // 0..15 = step within round
            int r = tid & 63;      // 0..63 = receiver
            if (recown[r]) outb[(e * G + s) * NREC_ + r] = recbuf[s][r];
        }
        // next recbuf writes are ordered behind exchange's two __syncthreads;
        // last round ends the kernel.
        if (e < ROUNDS - 1) exchange(e);
    }
}

extern "C" void kernel_launch(void* const* d_in, const int* in_sizes, int n_in,
                              void* d_out, int out_size, void* d_ws, size_t ws_size,
                              hipStream_t stream) {
    const float* x   = (const float*)d_in[0];
    const float* vp  = (const float*)d_in[1];
    const int*   src = (const int*)d_in[2];
    const int*   rec = (const int*)d_in[3];
    float*       o   = (float*)d_out;
    int*   flags = (int*)d_ws;
    float* gbuf  = (float*)((char*)d_ws + FLAGS_BYTES);
    (void)hipMemsetAsync(d_ws, 0, FLAGS_BYTES, stream);   // flags must start at 0
    hipLaunchKernelGGL(wave_reg_kernel, dim3(B_ * PIECES), dim3(1024), 0, stream,
                       x, vp, src, rec, o, flags, gbuf);
}

// Round 5
// 296.280 us; speedup vs baseline: 2.7599x; 1.1703x over previous
//
#include <hip/hip_runtime.h>

typedef float v4f __attribute__((ext_vector_type(4)));

namespace {
constexpr int B_     = 8;
constexpr int NT_    = 256;
constexpr int NX_    = 256;
constexpr int NREC_  = 64;
constexpr int PIECES = 16;             // R12: 128 blocks -> 128 CUs active
constexpr int IROWS  = 16;             // interior rows per strip
constexpr int G      = 16;             // ghost width = steps per round
constexpr int ROUNDS = NT_ / G;        // 16 (exchange count unchanged: 15)
constexpr int NB     = (IROWS + 2 * G) / 4;  // bands per block = 12
constexpr int NTHR   = NB * 64;        // 768 threads
constexpr int NBLK   = B_ * PIECES;    // 128 blocks
constexpr float DT2  = 1e-6f;          // DT*DT
constexpr float KLAP = 1e-8f;          // DT*DT/(DH*DH)
constexpr size_t FLAGS_BYTES = 4096;
constexpr int RCAP = 6;
} // namespace

// lane i <- lane i-1 (shfl_up 1). Lane 0 gets 0.0f (bound_ctrl) -- masked by cf=0.
__device__ __forceinline__ float dpp_shr1(float v) {
    return __int_as_float(__builtin_amdgcn_update_dpp(
        0, __float_as_int(v), 0x138 /*WAVE_SHR1*/, 0xF, 0xF, true));
}
// lane i <- lane i+1 (shfl_down 1). Lane 63 gets 0.0f -- masked by cf=0.
__device__ __forceinline__ float dpp_shl1(float v) {
    return __int_as_float(__builtin_amdgcn_update_dpp(
        0, __float_as_int(v), 0x130 /*WAVE_SHL1*/, 0xF, 0xF, true));
}

// R10: fence-free exchange via sc0 sc1 (system-coherent, bypasses non-coherent
// per-XCD L2s) -- killed the buffer_wbl2/inv storms (R9: 12-20us/exchange).
// R11: cf2 algebra (5 VALU/col); handshake restructure bought ~0 -> residue is
// invariant to handshake shape.
// R12: (1) wave-uniform branch-skip of receiver gather + source injection
// (they cost ~30us of VALU issue in ALL threads, used by ~1 thread/block);
// (2) re-scale to 128 blocks (PIECES=16, IROWS=16): redundancy 2x->3x but
// per-CU VALU 0.75x. Interior (16 rows) = ONE slab read by both neighbors.
__device__ __forceinline__ void store_v4_sys(float* p, v4f v) {
    asm volatile("global_store_dwordx4 %0, %1, off sc0 sc1"
                 :: "v"(p), "v"(v) : "memory");
}
__device__ __forceinline__ v4f load_v4_sys(const float* p) {
    v4f r;
    asm volatile("global_load_dwordx4 %0, %1, off sc0 sc1"
                 : "=v"(r) : "v"(p) : "memory");
    return r;
}

extern "C" __global__
__attribute__((amdgpu_flat_work_group_size(NTHR, NTHR), amdgpu_waves_per_eu(4, 4)))
void wave_reg_kernel(const float* __restrict__ x,
                     const float* __restrict__ vp,
                     const int* __restrict__ src_loc,
                     const int* __restrict__ rec_loc,
                     float* __restrict__ out,
                     int* __restrict__ flags,   // [128] monotone round counters
                     float* __restrict__ gbuf)  // [par2][128][lvl2][16][256]
{
    __shared__ float pub[2][2][NB][256];   // 48 KB: [par][top/bot row][band][col]
    __shared__ float wav[NT_];             // 1 KB wavelet
    __shared__ float recbuf[G][NREC_];     // 4 KB receiver staging (per round)
    __shared__ unsigned char recown[NREC_];// per-rec ownership of this block

    const int bid  = blockIdx.x;
    const int b    = bid & 7;
    const int p    = bid >> 3;             // 0..15
    const int blk  = b * PIECES + p;
    const int tid  = threadIdx.x;
    const int band = tid >> 6;             // wave id 0..11 -> 4 ext rows
    const int lane = tid & 63;
    const int c0   = lane << 2;            // first owned col (0..252)
    const int grt  = p * IROWS - G + (band << 2);  // global row of owned row 0

    if (tid < NT_) wav[tid] = x[b * NT_ + tid];
    if (tid < NREC_) {
        int rz = rec_loc[(b * NREC_ + tid) * 2 + 0];
        recown[tid] = (rz >= p * IROWS && rz < p * IROWS + IROWS) ? 1 : 0;
    }

    // cf = vp^2*DT^2/DH^2, zeroed at Dirichlet boundary + out-of-domain rows.
    // cf2 = 2 - 4*cf: hn = cf*((N+S)+(E+W)) + (cf2*C - P)  [5 VALU/col]
    v4f cf[4], cf2[4];
#pragma unroll
    for (int i = 0; i < 4; ++i) {
        int gr = grt + i;
        int crow = gr < 0 ? 0 : (gr > 255 ? 255 : gr);
        bool rowok = (gr >= 1) && (gr <= 254);
        v4f vv = *(const v4f*)&vp[crow * NX_ + c0];
        float cc[4];
#pragma unroll
        for (int k = 0; k < 4; ++k) {
            int col = c0 + k;
            float vk = (k == 0) ? vv.x : (k == 1) ? vv.y : (k == 2) ? vv.z : vv.w;
            cc[k] = (rowok && col >= 1 && col <= 254) ? vk * vk * KLAP : 0.f;
        }
        cf[i].x = cc[0]; cf[i].y = cc[1]; cf[i].z = cc[2]; cf[i].w = cc[3];
        cf2[i].x = 2.f - 4.f * cc[0]; cf2[i].y = 2.f - 4.f * cc[1];
        cf2[i].z = 2.f - 4.f * cc[2]; cf2[i].w = 2.f - 4.f * cc[3];
    }

    // source ownership (ghost rows included: ghost evolution must replay it)
    const int sz = src_loc[b * 2 + 0], sx = src_loc[b * 2 + 1];
    const int si = sz - grt;               // 0..3 if owned row
    const int sj = sx - c0;                // 0..3 if owned col
    const bool has_src = ((unsigned)si < 4u) && ((unsigned)sj < 4u);
    const bool wave_has_src = __any(has_src);   // wave-uniform -> branch skips

    // receiver slots: interior owner only (unique writer). pk=(r<<4)|(i<<2)|j
    int rs[RCAP]; int rcnt = 0;
#pragma unroll 1
    for (int r = 0; r < NREC_; ++r) {
        int rz = rec_loc[(b * NREC_ + r) * 2 + 0];
        int rx = rec_loc[(b * NREC_ + r) * 2 + 1];
        int i = rz - grt, j = rx - c0;
        if (rz >= p * IROWS && rz < p * IROWS + IROWS &&
            (unsigned)i < 4u && (unsigned)j < 4u) {
            if (rcnt < RCAP) rs[rcnt] = (r << 4) | (i << 2) | j;
            ++rcnt;
        }
    }
    if (rcnt > RCAP) rcnt = RCAP;
    const bool wave_has_rec = __any(rcnt > 0);  // wave-uniform -> branch skips
    float* outb = out + (size_t)b * NT_ * NREC_;

    v4f A[4], Bv[4];
    {
        v4f z = {0.f, 0.f, 0.f, 0.f};
#pragma unroll
        for (int i = 0; i < 4; ++i) { A[i] = z; Bv[i] = z; }
    }

    // gbuf slab pointer: [par][blk][lvl][row][col]; interior = the slab.
    auto gptr = [&](int e, int bk, int lvl, int rr) -> float* {
        return gbuf + ((((size_t)(e & 1) * NBLK + bk) * 2 + lvl) * 16 + rr) * 256;
    };

    // one step: P <- update(C, P); P becomes current. par = t&1.
    auto step = [&](v4f (&C)[4], v4f (&P)[4], int t, int par) {
        *(v4f*)&pub[par][0][band][c0] = C[0];   // my top row (south halo of band-1)
        *(v4f*)&pub[par][1][band][c0] = C[3];   // my bottom row (north halo of band+1)
        __syncthreads();
        v4f nn, ss;
        if (band > 0)      nn = *(const v4f*)&pub[par][1][band - 1][c0];
        else               { nn.x = 0.f; nn.y = 0.f; nn.z = 0.f; nn.w = 0.f; }
        if (band < NB - 1) ss = *(const v4f*)&pub[par][0][band + 1][c0];
        else               { ss.x = 0.f; ss.y = 0.f; ss.z = 0.f; ss.w = 0.f; }
#pragma unroll
        for (int i = 0; i < 4; ++i) {
            v4f n = (i == 0) ? nn : C[i - 1];
            v4f s = (i == 3) ? ss : C[i + 1];
            float wv = dpp_shr1(C[i].w);   // col c0-1 (lane0 -> 0: cf=0 masks)
            float ev = dpp_shl1(C[i].x);   // col c0+4 (lane63 -> 0: cf=0 masks)
            v4f hn;
            { float sm = (n.x + s.x) + (wv     + C[i].y);
              hn.x = fmaf(cf[i].x, sm, fmaf(cf2[i].x, C[i].x, -P[i].x)); }
            { float sm = (n.y + s.y) + (C[i].x + C[i].z);
              hn.y = fmaf(cf[i].y, sm, fmaf(cf2[i].y, C[i].y, -P[i].y)); }
            { float sm = (n.z + s.z) + (C[i].y + C[i].w);
              hn.z = fmaf(cf[i].z, sm, fmaf(cf2[i].z, C[i].z, -P[i].z)); }
            { float sm = (n.w + s.w) + (C[i].z + ev);
              hn.w = fmaf(cf[i].w, sm, fmaf(cf2[i].w, C[i].w, -P[i].w)); }
            P[i] = hn;
        }
        // source injection: only the wave containing the source pays for it
        if (wave_has_src) {
            const float sv = DT2 * wav[t];
#pragma unroll
            for (int i = 0; i < 4; ++i) {
                if (has_src && si == i) {
                    if      (sj == 0) P[i].x += sv;
                    else if (sj == 1) P[i].y += sv;
                    else if (sj == 2) P[i].z += sv;
                    else              P[i].w += sv;
                }
            }
        }
        // receiver gather (NEW level, registers) -> LDS staging. Only waves
        // containing receiver-owner threads execute this.
        if (wave_has_rec) {
#pragma unroll
            for (int k = 0; k < RCAP; ++k) {
                if (rcnt > k) {
                    int pk = rs[k];
                    int i = (pk >> 2) & 3, j = pk & 3, r = pk >> 4;
                    v4f t01 = (i & 1) ? P[1] : P[0];
                    v4f t23 = (i & 1) ? P[3] : P[2];
                    v4f rw  = (i & 2) ? t23 : t01;
                    float c01 = (j & 1) ? rw.y : rw.x;
                    float c23 = (j & 1) ? rw.w : rw.z;
                    recbuf[t & (G - 1)][r] = (j & 2) ? c23 : c01;
                }
            }
        }
        // no trailing barrier: next step uses pub[par^1] (parity double-buffer)
    };

    // early publish of prev level (Bv is final before the round's last step):
    // its store drain overlaps the final step's compute.
    auto publish_prev = [&](int e) {
        if (band >= 4 && band < 8) {       // interior bands
            int rr0 = (band - 4) << 2;
#pragma unroll
            for (int i = 0; i < 4; ++i)
                store_v4_sys(&gptr(e, blk, 1, rr0 + i)[c0], Bv[i]);
        }
    };

    // exchange after round e: publish cur level, drain via barrier's vmcnt(0),
    // flag (fire-and-forget), ghost waves poll their neighbor + refill.
    auto exchange = [&](int e) {
        if (band >= 4 && band < 8) {       // publish interior, cur level
            int rr0 = (band - 4) << 2;
#pragma unroll
            for (int i = 0; i < 4; ++i)
                store_v4_sys(&gptr(e, blk, 0, rr0 + i)[c0], A[i]);
        }
        // barrier semantics: each wave drains vmcnt(0) (all sc0 sc1 stores,
        // incl. early Bv publish, ack'd at coherence point) before s_barrier.
        __syncthreads();
        if (tid == 0)                      // fire-and-forget; neighbors poll
            __hip_atomic_store(&flags[blk], e + 1, __ATOMIC_RELAXED,
                               __HIP_MEMORY_SCOPE_SYSTEM);
        if (band < 4 && p > 0) {           // top ghost <- north (blk-1) interior
            if (lane == 0)
                while (__hip_atomic_load(&flags[blk - 1], __ATOMIC_RELAXED,
                                         __HIP_MEMORY_SCOPE_SYSTEM) < e + 1)
                    __builtin_amdgcn_s_sleep(1);
            int rr0 = band << 2;           // ext rows 0..15 == slab rows 0..15
#pragma unroll
            for (int i = 0; i < 4; ++i) {
                A[i]  = load_v4_sys(&gptr(e, blk - 1, 0, rr0 + i)[c0]);
                Bv[i] = load_v4_sys(&gptr(e, blk - 1, 1, rr0 + i)[c0]);
            }
        }
        if (band >= 8 && p < PIECES - 1) { // bottom ghost <- south (blk+1)
            if (lane == 0)
                while (__hip_atomic_load(&flags[blk + 1], __ATOMIC_RELAXED,
                                         __HIP_MEMORY_SCOPE_SYSTEM) < e + 1)
                    __builtin_amdgcn_s_sleep(1);
            int rr0 = (band - 8) << 2;     // ext rows 32..47 == slab rows 0..15
#pragma unroll
            for (int i = 0; i < 4; ++i) {
                A[i]  = load_v4_sys(&gptr(e, blk + 1, 0, rr0 + i)[c0]);
                Bv[i] = load_v4_sys(&gptr(e, blk + 1, 1, rr0 + i)[c0]);
            }
        }
        // asm loads are opaque to compiler waitcnt logic: drain before any use
        // of A/Bv and pin the order (rule #18).
        asm volatile("s_waitcnt vmcnt(0)" ::: "memory");
        __builtin_amdgcn_sched_barrier(0);
        __syncthreads();                   // all waves aligned for next round
    };

    int t = 0;
#pragma unroll 1
    for (int e = 0; e < ROUNDS; ++e) {
#pragma unroll 1
        for (int s = 0; s < G; s += 2) {
            step(A, Bv, t, 0);      // t even: cur=A, par=0
            if (s == G - 2 && e < ROUNDS - 1)
                publish_prev(e);    // Bv = lvl t_end-1 is final; overlap drain
            step(Bv, A, t + 1, 1);  // t odd:  cur=B, par=1
            t += 2;
        }
        // flush this round's receiver samples (G*NREC=1024 slots, 768 threads)
        __syncthreads();           // recbuf writes came from scattered owners
#pragma unroll 1
        for (int idx = tid; idx < G * NREC_; idx += NTHR) {
            int s = idx >> 6, r = idx & 63;
            if (recown[r]) outb[(e * G + s) * NREC_ + r] = recbuf[s][r];
        }
        // next recbuf writes are ordered behind exchange's barriers;
        // last round ends the kernel.
        if (e < ROUNDS - 1) exchange(e);
    }
}

extern "C" void kernel_launch(void* const* d_in, const int* in_sizes, int n_in,
                              void* d_out, int out_size, void* d_ws, size_t ws_size,
                              hipStream_t stream) {
    const float* x   = (const float*)d_in[0];
    const float* vp  = (const float*)d_in[1];
    const int*   src = (const int*)d_in[2];
    const int*   rec = (const int*)d_in[3];
    float*       o   = (float*)d_out;
    int*   flags = (int*)d_ws;
    float* gbuf  = (float*)((char*)d_ws + FLAGS_BYTES);
    (void)hipMemsetAsync(d_ws, 0, FLAGS_BYTES, stream);   // flags must start at 0
    hipLaunchKernelGGL(wave_reg_kernel, dim3(NBLK), dim3(NTHR), 0, stream,
                       x, vp, src, rec, o, flags, gbuf);
}

// Round 6
// 288.549 us; speedup vs baseline: 2.8339x; 1.0268x over previous
//
#include <hip/hip_runtime.h>

typedef float v4f __attribute__((ext_vector_type(4)));

namespace {
constexpr int B_     = 8;
constexpr int NT_    = 256;
constexpr int NX_    = 256;
constexpr int NREC_  = 64;
constexpr int PIECES = 16;             // 128 blocks -> 128 CUs active
constexpr int IROWS  = 16;             // interior rows per strip
constexpr int G      = 16;             // ghost width = steps per round
constexpr int ROUNDS = NT_ / G;        // 16 (15 exchanges)
constexpr int NB     = (IROWS + 2 * G) / 4;  // bands per block = 12
constexpr int NTHR   = NB * 64;        // 768 threads
constexpr int NBLK   = B_ * PIECES;    // 128 blocks
constexpr float DT2  = 1e-6f;          // DT*DT
constexpr float KLAP = 1e-8f;          // DT*DT/(DH*DH)
constexpr size_t FLAGS_BYTES = 4096;
constexpr int RCAP = 6;
} // namespace

// lane i <- lane i-1 (shfl_up 1). Lane 0 gets 0.0f (bound_ctrl) -- masked by cf=0.
__device__ __forceinline__ float dpp_shr1(float v) {
    return __int_as_float(__builtin_amdgcn_update_dpp(
        0, __float_as_int(v), 0x138 /*WAVE_SHR1*/, 0xF, 0xF, true));
}
// lane i <- lane i+1 (shfl_down 1). Lane 63 gets 0.0f -- masked by cf=0.
__device__ __forceinline__ float dpp_shl1(float v) {
    return __int_as_float(__builtin_amdgcn_update_dpp(
        0, __float_as_int(v), 0x130 /*WAVE_SHL1*/, 0xF, 0xF, true));
}

// R10: fence-free exchange via sc0 sc1 (system-coherent, bypasses non-coherent
// per-XCD L2s) -- killed the buffer_wbl2/inv storms.
// R12: 128 blocks, wave-uniform skip of src/rec blocks. Model validated:
// wall = VALU-issue (128us) + ~117us structural residue.
// R13: TRAPEZOID -- ghost row at distance d only influences the interior for
// the first G-d steps of a round. Exact per-band cutoffs (frontier-matched,
// bit-identical on the live path): compute iff k <= cut, publish iff
// k <= cut+1 (the +1 keeps the last consumer's halo fresh).
// cut = 4*band+3 (top ghost) | 16 (interior) | 47-4*band (bottom ghost).
// Ghost compute drops to 56% -> total VALU ~71%.
__device__ __forceinline__ void store_v4_sys(float* p, v4f v) {
    asm volatile("global_store_dwordx4 %0, %1, off sc0 sc1"
                 :: "v"(p), "v"(v) : "memory");
}
__device__ __forceinline__ v4f load_v4_sys(const float* p) {
    v4f r;
    asm volatile("global_load_dwordx4 %0, %1, off sc0 sc1"
                 : "=v"(r) : "v"(p) : "memory");
    return r;
}

extern "C" __global__
__attribute__((amdgpu_flat_work_group_size(NTHR, NTHR), amdgpu_waves_per_eu(4, 4)))
void wave_reg_kernel(const float* __restrict__ x,
                     const float* __restrict__ vp,
                     const int* __restrict__ src_loc,
                     const int* __restrict__ rec_loc,
                     float* __restrict__ out,
                     int* __restrict__ flags,   // [128] monotone round counters
                     float* __restrict__ gbuf)  // [par2][128][lvl2][16][256]
{
    __shared__ float pub[2][2][NB][256];   // 48 KB: [par][top/bot row][band][col]
    __shared__ float wav[NT_];             // 1 KB wavelet
    __shared__ float recbuf[G][NREC_];     // 4 KB receiver staging (per round)
    __shared__ unsigned char recown[NREC_];// per-rec ownership of this block

    const int bid  = blockIdx.x;
    const int b    = bid & 7;
    const int p    = bid >> 3;             // 0..15
    const int blk  = b * PIECES + p;
    const int tid  = threadIdx.x;
    const int band = tid >> 6;             // wave id 0..11 -> 4 ext rows
    const int lane = tid & 63;
    const int c0   = lane << 2;            // first owned col (0..252)
    const int grt  = p * IROWS - G + (band << 2);  // global row of owned row 0

    // trapezoid cutoff: band computes at in-round step k (1-based) iff k<=cut;
    // publishes iff k<=cut+1. Wave-uniform.
    const int cut = (band < 4) ? ((band << 2) + 3)
                  : ((band < 8) ? G : (47 - (band << 2)));

    if (tid < NT_) wav[tid] = x[b * NT_ + tid];
    if (tid < NREC_) {
        int rz = rec_loc[(b * NREC_ + tid) * 2 + 0];
        recown[tid] = (rz >= p * IROWS && rz < p * IROWS + IROWS) ? 1 : 0;
    }

    // cf = vp^2*DT^2/DH^2, zeroed at Dirichlet boundary + out-of-domain rows.
    // cf2 = 2 - 4*cf: hn = cf*((N+S)+(E+W)) + (cf2*C - P)  [5 VALU/col]
    v4f cf[4], cf2[4];
#pragma unroll
    for (int i = 0; i < 4; ++i) {
        int gr = grt + i;
        int crow = gr < 0 ? 0 : (gr > 255 ? 255 : gr);
        bool rowok = (gr >= 1) && (gr <= 254);
        v4f vv = *(const v4f*)&vp[crow * NX_ + c0];
        float cc[4];
#pragma unroll
        for (int k = 0; k < 4; ++k) {
            int col = c0 + k;
            float vk = (k == 0) ? vv.x : (k == 1) ? vv.y : (k == 2) ? vv.z : vv.w;
            cc[k] = (rowok && col >= 1 && col <= 254) ? vk * vk * KLAP : 0.f;
        }
        cf[i].x = cc[0]; cf[i].y = cc[1]; cf[i].z = cc[2]; cf[i].w = cc[3];
        cf2[i].x = 2.f - 4.f * cc[0]; cf2[i].y = 2.f - 4.f * cc[1];
        cf2[i].z = 2.f - 4.f * cc[2]; cf2[i].w = 2.f - 4.f * cc[3];
    }

    // source ownership (ghost rows included: ghost evolution must replay it)
    const int sz = src_loc[b * 2 + 0], sx = src_loc[b * 2 + 1];
    const int si = sz - grt;               // 0..3 if owned row
    const int sj = sx - c0;                // 0..3 if owned col
    const bool has_src = ((unsigned)si < 4u) && ((unsigned)sj < 4u);
    const bool wave_has_src = __any(has_src);   // wave-uniform -> branch skips

    // receiver slots: interior owner only (unique writer). pk=(r<<4)|(i<<2)|j
    int rs[RCAP]; int rcnt = 0;
#pragma unroll 1
    for (int r = 0; r < NREC_; ++r) {
        int rz = rec_loc[(b * NREC_ + r) * 2 + 0];
        int rx = rec_loc[(b * NREC_ + r) * 2 + 1];
        int i = rz - grt, j = rx - c0;
        if (rz >= p * IROWS && rz < p * IROWS + IROWS &&
            (unsigned)i < 4u && (unsigned)j < 4u) {
            if (rcnt < RCAP) rs[rcnt] = (r << 4) | (i << 2) | j;
            ++rcnt;
        }
    }
    if (rcnt > RCAP) rcnt = RCAP;
    const bool wave_has_rec = __any(rcnt > 0);  // wave-uniform -> branch skips
    float* outb = out + (size_t)b * NT_ * NREC_;

    v4f A[4], Bv[4];
    {
        v4f z = {0.f, 0.f, 0.f, 0.f};
#pragma unroll
        for (int i = 0; i < 4; ++i) { A[i] = z; Bv[i] = z; }
    }

    // gbuf slab pointer: [par][blk][lvl][row][col]; interior = the slab.
    auto gptr = [&](int e, int bk, int lvl, int rr) -> float* {
        return gbuf + ((((size_t)(e & 1) * NBLK + bk) * 2 + lvl) * 16 + rr) * 256;
    };

    // one step: P <- update(C, P); P becomes current. par = t&1.
    // k = in-round step (1..G), wave-uniform.
    auto step = [&](v4f (&C)[4], v4f (&P)[4], int t, int par) {
        const int k = (t & (G - 1)) + 1;
        if (k <= cut + 1) {                 // publish window = compute window +1
            *(v4f*)&pub[par][0][band][c0] = C[0];  // top row (south halo of band-1)
            *(v4f*)&pub[par][1][band][c0] = C[3];  // bottom row (north halo of band+1)
        }
        __syncthreads();
        if (k > cut) return;                // all this band's rows are dead now
        v4f nn, ss;
        if (band > 0)      nn = *(const v4f*)&pub[par][1][band - 1][c0];
        else               { nn.x = 0.f; nn.y = 0.f; nn.z = 0.f; nn.w = 0.f; }
        if (band < NB - 1) ss = *(const v4f*)&pub[par][0][band + 1][c0];
        else               { ss.x = 0.f; ss.y = 0.f; ss.z = 0.f; ss.w = 0.f; }
#pragma unroll
        for (int i = 0; i < 4; ++i) {
            v4f n = (i == 0) ? nn : C[i - 1];
            v4f s = (i == 3) ? ss : C[i + 1];
            float wv = dpp_shr1(C[i].w);   // col c0-1 (lane0 -> 0: cf=0 masks)
            float ev = dpp_shl1(C[i].x);   // col c0+4 (lane63 -> 0: cf=0 masks)
            v4f hn;
            { float sm = (n.x + s.x) + (wv     + C[i].y);
              hn.x = fmaf(cf[i].x, sm, fmaf(cf2[i].x, C[i].x, -P[i].x)); }
            { float sm = (n.y + s.y) + (C[i].x + C[i].z);
              hn.y = fmaf(cf[i].y, sm, fmaf(cf2[i].y, C[i].y, -P[i].y)); }
            { float sm = (n.z + s.z) + (C[i].y + C[i].w);
              hn.z = fmaf(cf[i].z, sm, fmaf(cf2[i].z, C[i].z, -P[i].z)); }
            { float sm = (n.w + s.w) + (C[i].z + ev);
              hn.w = fmaf(cf[i].w, sm, fmaf(cf2[i].w, C[i].w, -P[i].w)); }
            P[i] = hn;
        }
        // source injection: only the wave containing the source pays for it
        if (wave_has_src) {
            const float sv = DT2 * wav[t];
#pragma unroll
            for (int i = 0; i < 4; ++i) {
                if (has_src && si == i) {
                    if      (sj == 0) P[i].x += sv;
                    else if (sj == 1) P[i].y += sv;
                    else if (sj == 2) P[i].z += sv;
                    else              P[i].w += sv;
                }
            }
        }
        // receiver gather (NEW level, registers) -> LDS staging. Receiver
        // owners are interior bands only (always active).
        if (wave_has_rec) {
#pragma unroll
            for (int kk = 0; kk < RCAP; ++kk) {
                if (rcnt > kk) {
                    int pk = rs[kk];
                    int i = (pk >> 2) & 3, j = pk & 3, r = pk >> 4;
                    v4f t01 = (i & 1) ? P[1] : P[0];
                    v4f t23 = (i & 1) ? P[3] : P[2];
                    v4f rw  = (i & 2) ? t23 : t01;
                    float c01 = (j & 1) ? rw.y : rw.x;
                    float c23 = (j & 1) ? rw.w : rw.z;
                    recbuf[t & (G - 1)][r] = (j & 2) ? c23 : c01;
                }
            }
        }
        // no trailing barrier: next step uses pub[par^1] (parity double-buffer)
    };

    // early publish of prev level (Bv is final before the round's last step):
    // its store drain overlaps the final step's compute. Interior bands only.
    auto publish_prev = [&](int e) {
        if (band >= 4 && band < 8) {
            int rr0 = (band - 4) << 2;
#pragma unroll
            for (int i = 0; i < 4; ++i)
                store_v4_sys(&gptr(e, blk, 1, rr0 + i)[c0], Bv[i]);
        }
    };

    // exchange after round e: publish cur level, drain via barrier's vmcnt(0),
    // flag (fire-and-forget), ghost waves poll their neighbor + refill.
    auto exchange = [&](int e) {
        if (band >= 4 && band < 8) {       // publish interior, cur level
            int rr0 = (band - 4) << 2;
#pragma unroll
            for (int i = 0; i < 4; ++i)
                store_v4_sys(&gptr(e, blk, 0, rr0 + i)[c0], A[i]);
        }
        // barrier semantics: each wave drains vmcnt(0) (all sc0 sc1 stores,
        // incl. early Bv publish, ack'd at coherence point) before s_barrier.
        __syncthreads();
        if (tid == 0)                      // fire-and-forget; neighbors poll
            __hip_atomic_store(&flags[blk], e + 1, __ATOMIC_RELAXED,
                               __HIP_MEMORY_SCOPE_SYSTEM);
        if (band < 4 && p > 0) {           // top ghost <- north (blk-1) interior
            if (lane == 0)
                while (__hip_atomic_load(&flags[blk - 1], __ATOMIC_RELAXED,
                                         __HIP_MEMORY_SCOPE_SYSTEM) < e + 1)
                    __builtin_amdgcn_s_sleep(1);
            int rr0 = band << 2;           // ext rows 0..15 == slab rows 0..15
#pragma unroll
            for (int i = 0; i < 4; ++i) {
                A[i]  = load_v4_sys(&gptr(e, blk - 1, 0, rr0 + i)[c0]);
                Bv[i] = load_v4_sys(&gptr(e, blk - 1, 1, rr0 + i)[c0]);
            }
        }
        if (band >= 8 && p < PIECES - 1) { // bottom ghost <- south (blk+1)
            if (lane == 0)
                while (__hip_atomic_load(&flags[blk + 1], __ATOMIC_RELAXED,
                                         __HIP_MEMORY_SCOPE_SYSTEM) < e + 1)
                    __builtin_amdgcn_s_sleep(1);
            int rr0 = (band - 8) << 2;     // ext rows 32..47 == slab rows 0..15
#pragma unroll
            for (int i = 0; i < 4; ++i) {
                A[i]  = load_v4_sys(&gptr(e, blk + 1, 0, rr0 + i)[c0]);
                Bv[i] = load_v4_sys(&gptr(e, blk + 1, 1, rr0 + i)[c0]);
            }
        }
        // asm loads are opaque to compiler waitcnt logic: drain before any use
        // of A/Bv and pin the order (rule #18).
        asm volatile("s_waitcnt vmcnt(0)" ::: "memory");
        __builtin_amdgcn_sched_barrier(0);
        __syncthreads();                   // all waves aligned for next round
    };

    int t = 0;
#pragma unroll 1
    for (int e = 0; e < ROUNDS; ++e) {
#pragma unroll 1
        for (int s = 0; s < G; s += 2) {
            step(A, Bv, t, 0);      // t even: cur=A, par=0
            if (s == G - 2 && e < ROUNDS - 1)
                publish_prev(e);    // Bv = lvl t_end-1 is final; overlap drain
            step(Bv, A, t + 1, 1);  // t odd:  cur=B, par=1
            t += 2;
        }
        // flush this round's receiver samples (G*NREC=1024 slots, 768 threads)
        __syncthreads();           // recbuf writes came from scattered owners
#pragma unroll 1
        for (int idx = tid; idx < G * NREC_; idx += NTHR) {
            int s = idx >> 6, r = idx & 63;
            if (recown[r]) outb[(e * G + s) * NREC_ + r] = recbuf[s][r];
        }
        // next recbuf writes are ordered behind exchange's barriers;
        // last round ends the kernel.
        if (e < ROUNDS - 1) exchange(e);
    }
}

extern "C" void kernel_launch(void* const* d_in, const int* in_sizes, int n_in,
                              void* d_out, int out_size, void* d_ws, size_t ws_size,
                              hipStream_t stream) {
    const float* x   = (const float*)d_in[0];
    const float* vp  = (const float*)d_in[1];
    const int*   src = (const int*)d_in[2];
    const int*   rec = (const int*)d_in[3];
    float*       o   = (float*)d_out;
    int*   flags = (int*)d_ws;
    float* gbuf  = (float*)((char*)d_ws + FLAGS_BYTES);
    (void)hipMemsetAsync(d_ws, 0, FLAGS_BYTES, stream);   // flags must start at 0
    hipLaunchKernelGGL(wave_reg_kernel, dim3(NBLK), dim3(NTHR), 0, stream,
                       x, vp, src, rec, o, flags, gbuf);
}